// Round 9
// baseline (278.404 us; speedup 1.0000x reference)
//
#include <hip/hip_runtime.h>
#include <hip/hip_bf16.h>

#define BATCH 16384
#define HID   1024
#define EMBD  512
#define NOPS  8
#define MAXT  136   // max tile slots: sum ceil(cnt_e/128) <= 135
#define CNTS  16    // cnt stride in ints (64 B) — one cache line per expert

typedef __attribute__((ext_vector_type(8))) short bf16x8;
typedef __attribute__((ext_vector_type(4))) float f32x4;

#define VMWAIT(N) asm volatile("s_waitcnt vmcnt(" #N ")" ::: "memory")
// raw s_barrier is NO-MEM to LLVM IR (that's why __syncthreads wraps it in
// fences) and sched_barrier(0) only constrains the MIR scheduler — IR passes
// can hoist LDS reads / global_load_lds issues above the barrier (round-6
// absmax fail). Empty asm with "memory" clobber = zero-inst compiler fence.
#define BARRIER_FENCED()                      \
  do {                                        \
    asm volatile("" ::: "memory");            \
    __builtin_amdgcn_s_barrier();             \
    asm volatile("" ::: "memory");            \
    __builtin_amdgcn_sched_barrier(0);        \
  } while (0)

__device__ __forceinline__ unsigned short f2bf(float f) {
  unsigned int u = __float_as_uint(f);
  u += 0x7FFF + ((u >> 16) & 1);
  return (unsigned short)(u >> 16);
}

__device__ __forceinline__ unsigned int pk2(float a, float b) {
  __hip_bfloat162 t = __float22bfloat162_rn(make_float2(a, b));
  return *(unsigned int*)(&t);
}

__device__ __forceinline__ void lds_load16(void* lds, const void* g) {
  __builtin_amdgcn_global_load_lds(
      (const __attribute__((address_space(1))) unsigned int*)g,
      (__attribute__((address_space(3))) unsigned int*)lds, 16, 0, 0);
}

// XCD-locality decode on the DENSE gemm index gb (0..1087). Physical bid is
// 3*gb (period-3 rider interleave), and 3 is invertible mod 8, so all gb with
// equal gb&7 still land on one XCD — locality grouping survives the remap.
__device__ __forceinline__ void decode_bid(int gb, int& g, int& nx) {
  g = 17 * (gb & 7) + (gb >> 6);
  nx = (gb >> 3) & 7;
}

// schedule_k replacement: each block derives (e, rs) for its tile g from the
// 8 cnt values with a scalar prefix scan (uniform -> SGPR). Returns -1 if
// g >= total tile count.
__device__ __forceinline__ int decode_tile(const int* __restrict__ cnt,
                                           int g, int& rs, int& ce_cnt) {
  int e = -1, at = 0;
  rs = 0; ce_cnt = 0;
#pragma unroll
  for (int o = 0; o < NOPS; ++o) {
    int c = cnt[o * CNTS];
    int t = (c + 127) >> 7;
    if (e < 0 && g < at + t) { e = o; rs = (g - at) * 128; ce_cnt = c; }
    at += t;
  }
  return e;
}

// LDS-free weight transpose tile, fq-major slab layout:
//   slab[kq][n][kk] bf16 (kq=k/8 in 0..3, n in 0..127, kk=k%8)
//   value = W[ks*32 + kq*8 + kk][nx*128 + n]
// Fragment ds_read (fq*128+row)*16B: consecutive 8 lanes cover a full 128B
// stripe -> conflict-free.
__device__ __forceinline__ void w_prep_tile(const float* __restrict__ W,
                                            short* __restrict__ Wp,
                                            int ks, int nx, int tid) {
  int n = tid & 127, kh = tid >> 7;           // kh: low/high 16 of the 32-k tile
  const float* src = W + (size_t)(ks * 32 + kh * 16) * 1024 + nx * 128 + n;
  float v[16];
#pragma unroll
  for (int kk = 0; kk < 16; ++kk) v[kk] = src[(size_t)kk * 1024];
  uint4 a, b;
  a.x = pk2(v[0], v[1]);  a.y = pk2(v[2], v[3]);
  a.z = pk2(v[4], v[5]);  a.w = pk2(v[6], v[7]);
  b.x = pk2(v[8], v[9]);  b.y = pk2(v[10], v[11]);
  b.z = pk2(v[12], v[13]); b.w = pk2(v[14], v[15]);
  uint4* dst = (uint4*)Wp;
  dst[(2 * kh) * 128 + n]     = a;            // kq = 2*kh   (k 0..7 of this half)
  dst[(2 * kh + 1) * 128 + n] = b;            // kq = 2*kh+1 (k 8..15)
}

// ---- phase 0: bucket (64) + ce (128) + W1 prep (2048) + xb convert (4096) ---
// Period-3 INTERLEAVE (round-9): bids with r!=0 are xb-convert, r==0 are
// bucket/ce/W1prep — previously xb (bids 2240+) ran serially AFTER the others
// because blocks dispatch in bid order; mixing them per-CU overlaps xb's
// memory streaming with W1prep's VALU packing.
// xb = bf16(x) in token order — gemm1 gathers A rows straight from xb.
// ce[e][n] = b1[e][n] + sum_k emb[e][k] * W1[e][1024+k][n] — embedding half of
// GEMM1 collapses to a per-(expert,n) constant, cutting GEMM1 K 1536 -> 1024.
__global__ void bucket_ce_k(const int* __restrict__ ops, int* __restrict__ cnt,
                            int* __restrict__ idx, const float* __restrict__ W1,
                            const float* __restrict__ emb,
                            const float* __restrict__ b1, float* __restrict__ ce,
                            short* __restrict__ W1p, const float* __restrict__ x,
                            unsigned int* __restrict__ xb) {
  int bid = blockIdx.x;
  int tid = threadIdx.x;
  int q = bid / 3, r = bid - q * 3;
  if (r != 0) {
    // ---- xb path: f32 -> bf16, slots 2*q+(r-1) in 0..4479, 4096 real ----
    int b = 2 * q + (r - 1);
    if (b >= 4096) return;
    size_t i = ((size_t)b * 256 + tid) * 16;
    const float4* src = (const float4*)(x + i);
    float4 f0 = src[0], f1 = src[1], f2v = src[2], f3 = src[3];
    uint4 p0 = make_uint4(pk2(f0.x, f0.y), pk2(f0.z, f0.w),
                          pk2(f1.x, f1.y), pk2(f1.z, f1.w));
    uint4 p1 = make_uint4(pk2(f2v.x, f2v.y), pk2(f2v.z, f2v.w),
                          pk2(f3.x, f3.y), pk2(f3.z, f3.w));
    uint4* dst = (uint4*)(xb + i / 2);
    dst[0] = p0;
    dst[1] = p1;
    return;
  }
  // ---- "other" lane: q in 0..2239 -> bucket(64) | ce(128) | W1prep(2048) ----
  if (q >= 192) {
    int b = q - 192;
    int e = b / 256; int rr = b % 256; int nx = rr / 32, ks = rr % 32;
    w_prep_tile(W1 + (size_t)e * 1536 * 1024,
                W1p + ((size_t)(e * 8 + nx) * 32 + ks) * 4096, ks, nx, tid);
    return;
  }
  if (q >= 64) {
    // ---- ce path ----
    int cb = q - 64;
    int e = cb >> 4, kp = cb & 15;
    int n = tid * 4;
    const float* Wc = W1 + (size_t)e * 1536 * 1024 + (size_t)(1024 + kp * 32) * 1024 + n;
    const float* ee = emb + e * EMBD + kp * 32;
    float4 a = make_float4(0.f, 0.f, 0.f, 0.f);
#pragma unroll
    for (int kk = 0; kk < 32; ++kk) {
      float s = ee[kk];
      float4 r2 = *(const float4*)(Wc + (size_t)kk * 1024);
      a.x += s * r2.x; a.y += s * r2.y; a.z += s * r2.z; a.w += s * r2.w;
    }
    if (kp == 0) {
      float4 b = *(const float4*)(b1 + e * HID + n);
      a.x += b.x; a.y += b.y; a.z += b.z; a.w += b.w;
    }
    float* d = ce + e * HID + n;
    atomicAdd(d + 0, a.x); atomicAdd(d + 1, a.y);
    atomicAdd(d + 2, a.z); atomicAdd(d + 3, a.w);
    return;
  }
  // ---- bucket path (block-aggregated atomics), q in 0..63 ----
  __shared__ int wcnt[4][NOPS];
  __shared__ int wbase[4][NOPS];
  int lane = tid & 63, w = tid >> 6;
  int t = q * 256 + tid;
  int op = ops[t];
  unsigned long long msave = 0;
#pragma unroll
  for (int o = 0; o < NOPS; ++o) {
    unsigned long long mm = __ballot(op == o);
    if (op == o) msave = mm;
    if (lane == o) wcnt[w][o] = __popcll(mm);
  }
  __syncthreads();
  if (tid < NOPS) {
    int c0 = wcnt[0][tid], c1 = wcnt[1][tid], c2 = wcnt[2][tid], c3 = wcnt[3][tid];
    int base = atomicAdd(&cnt[tid * CNTS], c0 + c1 + c2 + c3);
    wbase[0][tid] = base;
    wbase[1][tid] = base + c0;
    wbase[2][tid] = base + c0 + c1;
    wbase[3][tid] = base + c0 + c1 + c2;
  }
  __syncthreads();
  int pre = __popcll(msave & ((1ull << lane) - 1ull));
  idx[op * BATCH + wbase[w][op] + pre] = t;
}

// ---------------- phase 1: GEMM1 gathered-DMA A + W2 prep, INTERLEAVED -------
// h = relu(x_tile @ W1[e][:1024] + ce[e]); K = 1024 (32 iters).
// Period-3 bid interleave (round-9): r==0 -> gemm (gb=q dense 0..1087),
// r!=0 -> W2-prep slot 2q+(r-1) (2176 slots, 2048 real). Previously prep bids
// 1088+ dispatched AFTER all gemm blocks -> serial tail that deflated both
// MfmaUtil and VALUBusy; mixing gives every CU gemm+prep co-residency.
// LINE-MERGED A-gather (round-8): 4 consecutive lanes fetch the 4 16B
// quarters of ONE token row's 64B ks-slice -> same-line requests merge.
// Source k-quarter XOR-swizzled by (row>>1)&3 so fragment ds_reads are
// conflict-free (rule #21 pre-swizzled-source pattern).
__global__ __launch_bounds__(256, 3) void gemm1_w2_k(
    const unsigned int* __restrict__ xb, const int* __restrict__ idx,
    const float* __restrict__ ce, const short* __restrict__ W1p,
    unsigned short* __restrict__ hp, const int* __restrict__ cnt,
    const float* __restrict__ W2, short* __restrict__ W2p) {
  int bid = blockIdx.x;
  int tid = threadIdx.x;
  int q = bid / 3, r = bid - q * 3;
  if (r != 0) {
    // ---- W2 path: slots 2q+(r-1) in 0..2175, 2048 real ----
    int b = 2 * q + (r - 1);
    if (b >= 2048) return;
    int e = b / 256; int rr = b % 256; int nx = rr / 32, ks = rr % 32;
    w_prep_tile(W2 + (size_t)e * 1024 * 1024,
                W2p + ((size_t)(e * 8 + nx) * 32 + ks) * 4096, ks, nx, tid);
    return;
  }
  int g, nx;
  decode_bid(q, g, nx);
  int rs, ce_cnt;
  int e = decode_tile(cnt, g, rs, ce_cnt);
  if (e < 0) return;

  __shared__ __align__(16) char smem[49152];   // 3 x (8KB A + 8KB B)
  char* s0 = smem;
  char* s1 = smem + 16384;
  char* s2 = smem + 32768;

  int lane = tid & 63, w = tid >> 6;
  int wm = w >> 1, wn = w & 1;
  int fr = lane & 15, fq = lane >> 4;

  // A-gather roles: wave w stages rows w*32 .. w*32+31 (2 instrs of 16 rows).
  // lane -> (row_local = lane>>2, phys quarter = lane&3); source k-quarter is
  // XOR-swizzled: q_src = (lane&3) ^ ((lane>>3)&3)  [= phys ^ ((row>>1)&3)].
  int r0 = w * 32 + (lane >> 2);
  int r1 = r0 + 16;
  int qs = (lane & 3) ^ ((lane >> 3) & 3);
  int pp0 = rs + r0, pp1 = rs + r1;
  int t0 = (pp0 < ce_cnt) ? idx[e * BATCH + pp0] : 0;
  int t1 = (pp1 < ce_cnt) ? idx[e * BATCH + pp1] : 0;
  const char* pa0 = (const char*)xb + (size_t)t0 * 2048 + qs * 16;
  const char* pa1 = (const char*)xb + (size_t)t1 * 2048 + qs * 16;
  const char* pb0 = (const char*)W1p + (size_t)(e * 8 + nx) * 32 * 8192
                    + w * 1024 + lane * 16;
  const char* pb1 = pb0 + 4096;

#define G1_STAGE(NB)                                                          \
  {                                                                           \
    lds_load16((NB) + w * 2048,         pa0);                                 \
    lds_load16((NB) + w * 2048 + 1024,  pa1);                                 \
    lds_load16((NB) + 8192 + w * 1024,  pb0);                                 \
    lds_load16((NB) + 12288 + w * 1024, pb1);                                 \
    pa0 += 64; pa1 += 64; pb0 += 8192; pb1 += 8192;                           \
  }

#define G1_COMP(CB)                                                           \
  {                                                                           \
    const short* lA_ = (const short*)(CB);                                    \
    const short* lB_ = (const short*)((CB) + 8192);                           \
    bf16x8 af[4], bfr[4];                                                     \
    _Pragma("unroll")                                                         \
    for (int i = 0; i < 4; ++i) af[i] = *(const bf16x8*)&lA_[fo + i * 512];   \
    _Pragma("unroll")                                                         \
    for (int j = 0; j < 4; ++j) bfr[j] = *(const bf16x8*)&lB_[bo + j * 128];  \
    _Pragma("unroll")                                                         \
    for (int i = 0; i < 4; ++i)                                               \
      _Pragma("unroll")                                                       \
      for (int j = 0; j < 4; ++j)                                             \
        acc[i][j] = __builtin_amdgcn_mfma_f32_16x16x32_bf16(af[i], bfr[j],    \
                                                            acc[i][j], 0, 0, 0); \
  }

#define G1_STEP(CB, NB)                                                       \
  {                                                                           \
    G1_STAGE(NB);                                                             \
    G1_COMP(CB);                                                              \
    VMWAIT(4);                                                                \
    BARRIER_FENCED();                                                         \
  }

  // prologue: stage ks=0 -> s0, ks=1 -> s1; wait for s0 only (4 in flight)
  G1_STAGE(s0);
  G1_STAGE(s1);
  VMWAIT(4);
  BARRIER_FENCED();

  f32x4 acc[4][4] = {};
  // A frag (row-major + quarter swizzle): row = wm*64+i*16+fr, phys quarter
  // q' = fq ^ ((fr>>1)&3)  [(row>>1)&3 == (fr>>1)&3 since wm*64,i*16 ≡ 0 mod 8]
  int fo = (wm * 64 + fr) * 32 + (fq ^ ((fr >> 1) & 3)) * 8;  // shorts, +i*512
  int bo = (fq * 128 + wn * 64 + fr) * 8;                     // B-frag base

  for (int it = 0; it < 10; ++it) {         // ks = 0..29
    G1_STEP(s0, s2);
    G1_STEP(s1, s0);
    G1_STEP(s2, s1);
  }
  // ks = 30: nothing left to stage; need ks=31's loads (into s1) complete
  G1_COMP(s0);
  VMWAIT(0);
  BARRIER_FENCED();
  // ks = 31
  G1_COMP(s1);

#undef G1_STEP
#undef G1_COMP
#undef G1_STAGE

  // epilogue: +ce (bias incl. embedding term) + relu + bf16, coalesced via LDS.
  // hp layout (fq-major): [g][ks2(32)][kq(4)][128 r][8 k] — gemm2 staging is a
  // linear 8 KB slab copy. LDS round-trip gets a 1-bit XOR swizzle.
  float bias[4];
#pragma unroll
  for (int j = 0; j < 4; ++j)
    bias[j] = ce[e * HID + nx * 128 + wn * 64 + j * 16 + fr];

  int lr = lane >> 2;
#pragma unroll
  for (int i = 0; i < 4; ++i) {
    __syncthreads();
#pragma unroll
    for (int j = 0; j < 4; ++j)
#pragma unroll
      for (int rg = 0; rg < 4; ++rg) {
        float v = acc[i][j][rg] + bias[j];
        v = v > 0.f ? v : 0.f;
        int row16 = fq * 4 + rg;
        int off = w * 2048 + row16 * 128 + (j * 16 + fr) * 2;
        off ^= (row16 & 1) << 6;
        *(unsigned short*)(smem + off) = f2bf(v);
      }
    __syncthreads();
    int R = wm * 64 + i * 16 + lr;
#pragma unroll
    for (int s = 0; s < 2; ++s) {
      int ch = (lane & 3) + s * 4;
      int off = w * 2048 + lr * 128 + ch * 16;
      off ^= (lr & 1) << 6;
      uint4 val = *(const uint4*)(smem + off);
      int ks2 = nx * 4 + wn * 2 + (ch >> 2);
      int kq = ch & 3;
      *(uint4*)(hp + (((size_t)(g * 32 + ks2) * 4 + kq) * 128 + R) * 8) = val;
    }
  }
}

// ---------------- phase 2: GEMM2  out[tok] = relu(h @ W2[e] + b2[e]) ---------
__global__ __launch_bounds__(256, 3) void gemm2_k(
    const unsigned short* __restrict__ hp, const float* __restrict__ b2,
    const short* __restrict__ W2p, float* __restrict__ out,
    const int* __restrict__ idx, const int* __restrict__ cnt) {
  int g, nx;
  decode_bid(blockIdx.x, g, nx);
  int rs, ce_cnt;
  int e = decode_tile(cnt, g, rs, ce_cnt);
  if (e < 0) return;

  __shared__ __align__(16) char smem[49152];   // 3 x (8KB A + 8KB B)
  __shared__ int toks[128];
  char* s0 = smem;
  char* s1 = smem + 16384;
  char* s2 = smem + 32768;

  int tid = threadIdx.x, lane = tid & 63, w = tid >> 6;
  int wm = w >> 1, wn = w & 1;
  int fr = lane & 15, fq = lane >> 4;

  if (tid < 128) {
    int p = rs + tid;
    toks[tid] = (p < ce_cnt) ? idx[e * BATCH + p] : 0;
  }

  const char* Asrc = (const char*)hp + (size_t)g * 32 * 8192;
  const char* Bsrc = (const char*)W2p + (size_t)(e * 8 + nx) * 32 * 8192;
  const char* pA0 = Asrc + w * 1024 + lane * 16;
  const char* pA1 = pA0 + 4096;
  const char* pB0 = Bsrc + w * 1024 + lane * 16;
  const char* pB1 = pB0 + 4096;

#define G2_STAGE(NB)                                                          \
  {                                                                           \
    lds_load16((NB) + w * 1024,         pA0);                                 \
    lds_load16((NB) + 4096 + w * 1024,  pA1);                                 \
    lds_load16((NB) + 8192 + w * 1024,  pB0);                                 \
    lds_load16((NB) + 12288 + w * 1024, pB1);                                 \
    pA0 += 8192; pA1 += 8192; pB0 += 8192; pB1 += 8192;                       \
  }

#define G2_COMP(CB)                                                           \
  {                                                                           \
    const short* lA_ = (const short*)(CB);                                    \
    const short* lB_ = (const short*)((CB) + 8192);                           \
    bf16x8 af[4], bfr[4];                                                     \
    _Pragma("unroll")                                                         \
    for (int i = 0; i < 4; ++i) af[i] = *(const bf16x8*)&lA_[fo + i * 128];   \
    _Pragma("unroll")                                                         \
    for (int j = 0; j < 4; ++j) bfr[j] = *(const bf16x8*)&lB_[bo + j * 128];  \
    _Pragma("unroll")                                                         \
    for (int i = 0; i < 4; ++i)                                               \
      _Pragma("unroll")                                                       \
      for (int j = 0; j < 4; ++j)                                             \
        acc[i][j] = __builtin_amdgcn_mfma_f32_16x16x32_bf16(af[i], bfr[j],    \
                                                            acc[i][j], 0, 0, 0); \
  }

#define G2_STEP(CB, NB)                                                       \
  {                                                                           \
    G2_STAGE(NB);                                                             \
    G2_COMP(CB);                                                              \
    VMWAIT(4);                                                                \
    BARRIER_FENCED();                                                         \
  }

  // prologue: stage ks=0 -> s0, ks=1 -> s1
  G2_STAGE(s0);
  G2_STAGE(s1);
  VMWAIT(4);
  BARRIER_FENCED();

  f32x4 acc[4][4] = {};
  int fo = (fq * 128 + wm * 64 + fr) * 8;
  int bo = (fq * 128 + wn * 64 + fr) * 8;

  for (int it = 0; it < 10; ++it) {         // ks = 0..29
    G2_STEP(s0, s2);
    G2_STEP(s1, s0);
    G2_STEP(s2, s1);
  }
  G2_COMP(s0);          // ks = 30
  VMWAIT(0);
  BARRIER_FENCED();
  G2_COMP(s1);          // ks = 31

#undef G2_STEP
#undef G2_COMP
#undef G2_STAGE

  // epilogue: bias + relu + scatter to out rows, coalesced via LDS round-trip.
  float bias[4];
#pragma unroll
  for (int j = 0; j < 4; ++j)
    bias[j] = b2[e * HID + nx * 128 + wn * 64 + j * 16 + fr];

  int lr = lane >> 2;
#pragma unroll
  for (int i = 0; i < 4; ++i) {
    __syncthreads();
#pragma unroll
    for (int j = 0; j < 4; ++j)
#pragma unroll
      for (int rg = 0; rg < 4; ++rg) {
        float v = acc[i][j][rg] + bias[j];
        int row16 = fq * 4 + rg;
        int off = w * 4096 + row16 * 256 + (j * 16 + fr) * 4;
        off ^= (row16 & 1) << 6;
        *(float*)(smem + off) = v > 0.f ? v : 0.f;
      }
    __syncthreads();
    int R = wm * 64 + i * 16 + lr;
    if (R < ce_cnt - rs) {
      float* orow = out + (size_t)toks[R] * HID + nx * 128 + wn * 64;
#pragma unroll
      for (int s = 0; s < 4; ++s) {
        int ch = (lane & 3) + s * 4;
        int off = w * 4096 + lr * 256 + ch * 16;
        off ^= (lr & 1) << 6;
        *(float4*)(orow + ch * 4) = *(const float4*)(smem + off);
      }
    }
  }
}

// ---------------- workspace layout (bytes) ----------------
// cnt     @ 0          (512)          — zeroed (with ce) by one memset
// ce      @ 512        (32768)        -> 33280
// idx     @ 36864      (524288)       -> 561152
// W1p     @ 561152     (16777216)     -> 17338368
// W2p     @ 17338368   (16777216)     -> 34115584
// hp      @ 34115584   (35651584)     -> 69767168
// xb      @ 69767168   (33554432)     -> 103321600 (~103.3 MB)

extern "C" void kernel_launch(void* const* d_in, const int* in_sizes, int n_in,
                              void* d_out, int out_size, void* d_ws, size_t ws_size,
                              hipStream_t stream) {
  const float* x   = (const float*)d_in[0];
  const int*   ops = (const int*)d_in[1];
  const float* emb = (const float*)d_in[2];
  const float* W1  = (const float*)d_in[3];
  const float* b1  = (const float*)d_in[4];
  const float* W2  = (const float*)d_in[5];
  const float* b2  = (const float*)d_in[6];
  float* out = (float*)d_out;

  char* ws = (char*)d_ws;
  int* cnt  = (int*)(ws + 0);
  float* ce = (float*)(ws + 512);
  int* idx  = (int*)(ws + 36864);
  short* W1p = (short*)(ws + 561152);
  short* W2p = (short*)(ws + 17338368);
  unsigned short* hp = (unsigned short*)(ws + 34115584);
  unsigned int* xb = (unsigned int*)(ws + 69767168);

  hipMemsetAsync(ws, 0, 33280, stream);   // cnt + ce
  // phase 0: period-3 interleave, 2240 "other" + 4480 xb slots = 6720 blocks
  bucket_ce_k<<<6720, 256, 0, stream>>>(ops, cnt, idx, W1, emb, b1, ce, W1p, x, xb);
  // phase 1: period-3 interleave, 1088 gemm + 2176 W2-prep slots = 3264 blocks
  gemm1_w2_k<<<3264, 256, 0, stream>>>(xb, idx, ce, W1p, hp, cnt, W2, W2p);
  gemm2_k<<<8 * MAXT, 256, 0, stream>>>(hp, b2, W2p, out, idx, cnt);
}

// Round 10
// 273.251 us; speedup vs baseline: 1.0189x; 1.0189x over previous
//
#include <hip/hip_runtime.h>
#include <hip/hip_bf16.h>

#define BATCH 16384
#define HID   1024
#define EMBD  512
#define NOPS  8
#define MAXT  136   // max tile slots: sum ceil(cnt_e/128) <= 135
#define CNTS  16    // cnt stride in ints (64 B) — one cache line per expert

typedef __attribute__((ext_vector_type(8))) short bf16x8;
typedef __attribute__((ext_vector_type(4))) float f32x4;

#define VMWAIT(N) asm volatile("s_waitcnt vmcnt(" #N ")" ::: "memory")
// raw s_barrier is NO-MEM to LLVM IR; empty "memory"-clobber asm on both
// sides = zero-inst compiler fence (round-6 lesson: sched_barrier(0) alone
// does not stop IR-level hoisting of LDS reads / DMA issues past the barrier).
#define BARRIER_FENCED()                      \
  do {                                        \
    asm volatile("" ::: "memory");            \
    __builtin_amdgcn_s_barrier();             \
    asm volatile("" ::: "memory");            \
    __builtin_amdgcn_sched_barrier(0);        \
  } while (0)

__device__ __forceinline__ unsigned short f2bf(float f) {
  unsigned int u = __float_as_uint(f);
  u += 0x7FFF + ((u >> 16) & 1);
  return (unsigned short)(u >> 16);
}

__device__ __forceinline__ unsigned int pk2(float a, float b) {
  __hip_bfloat162 t = __float22bfloat162_rn(make_float2(a, b));
  return *(unsigned int*)(&t);
}

__device__ __forceinline__ void lds_load16(void* lds, const void* g) {
  __builtin_amdgcn_global_load_lds(
      (const __attribute__((address_space(1))) unsigned int*)g,
      (__attribute__((address_space(3))) unsigned int*)lds, 16, 0, 0);
}

// XCD-locality decode, 1088-block form (gemm2): bid&7 = XCD class.
__device__ __forceinline__ void decode_bid(int bid, int& g, int& nx) {
  g = 17 * (bid & 7) + (bid >> 6);
  nx = (bid >> 3) & 7;
}

// 544-block form (gemm1, 128x256 tiles): gb&7 = XCD class; 4 nx-pairs per g.
__device__ __forceinline__ void decode_bid2(int gb, int& g, int& nx2) {
  g = 17 * (gb & 7) + (gb >> 5);
  nx2 = (gb >> 3) & 3;
}

// schedule_k replacement: derive (e, rs) for tile g from the 8 cnt values via
// scalar prefix scan (uniform -> SGPR). Returns -1 if g >= tile count.
__device__ __forceinline__ int decode_tile(const int* __restrict__ cnt,
                                           int g, int& rs, int& ce_cnt) {
  int e = -1, at = 0;
  rs = 0; ce_cnt = 0;
#pragma unroll
  for (int o = 0; o < NOPS; ++o) {
    int c = cnt[o * CNTS];
    int t = (c + 127) >> 7;
    if (e < 0 && g < at + t) { e = o; rs = (g - at) * 128; ce_cnt = c; }
    at += t;
  }
  return e;
}

// LDS-free weight transpose tile, fq-major slab layout:
//   slab[kq][n][kk] bf16 (kq=k/8 in 0..3, n in 0..127, kk=k%8)
//   value = W[ks*32 + kq*8 + kk][nx*128 + n]
// Fragment ds_read (fq*128+row)*16B: consecutive 8 lanes cover a full 128B
// stripe -> conflict-free.
__device__ __forceinline__ void w_prep_tile(const float* __restrict__ W,
                                            short* __restrict__ Wp,
                                            int ks, int nx, int tid) {
  int n = tid & 127, kh = tid >> 7;           // kh: low/high 16 of the 32-k tile
  const float* src = W + (size_t)(ks * 32 + kh * 16) * 1024 + nx * 128 + n;
  float v[16];
#pragma unroll
  for (int kk = 0; kk < 16; ++kk) v[kk] = src[(size_t)kk * 1024];
  uint4 a, b;
  a.x = pk2(v[0], v[1]);  a.y = pk2(v[2], v[3]);
  a.z = pk2(v[4], v[5]);  a.w = pk2(v[6], v[7]);
  b.x = pk2(v[8], v[9]);  b.y = pk2(v[10], v[11]);
  b.z = pk2(v[12], v[13]); b.w = pk2(v[14], v[15]);
  uint4* dst = (uint4*)Wp;
  dst[(2 * kh) * 128 + n]     = a;            // kq = 2*kh   (k 0..7 of this half)
  dst[(2 * kh + 1) * 128 + n] = b;            // kq = 2*kh+1 (k 8..15)
}

// ---- phase 0 (round-8 ordering — round-9 interleave HURT, reverted):
// bucket (64) + ce (128) + W1 prep (2048) + xb convert (4096, tail backfill).
// xb = bf16(x) in token order; gemm1 gathers A rows from xb via DMA.
// ce[e][n] = b1[e][n] + sum_k emb[e][k] * W1[e][1024+k][n].
__global__ void bucket_ce_k(const int* __restrict__ ops, int* __restrict__ cnt,
                            int* __restrict__ idx, const float* __restrict__ W1,
                            const float* __restrict__ emb,
                            const float* __restrict__ b1, float* __restrict__ ce,
                            short* __restrict__ W1p, const float* __restrict__ x,
                            unsigned int* __restrict__ xb) {
  int bid = blockIdx.x;
  int tid = threadIdx.x;
  if (bid >= 2240) {
    // ---- xb path: f32 -> bf16, 4096 blocks * 4096 elems ----
    size_t i = ((size_t)(bid - 2240) * 256 + tid) * 16;
    const float4* src = (const float4*)(x + i);
    float4 f0 = src[0], f1 = src[1], f2v = src[2], f3 = src[3];
    uint4 p0 = make_uint4(pk2(f0.x, f0.y), pk2(f0.z, f0.w),
                          pk2(f1.x, f1.y), pk2(f1.z, f1.w));
    uint4 p1 = make_uint4(pk2(f2v.x, f2v.y), pk2(f2v.z, f2v.w),
                          pk2(f3.x, f3.y), pk2(f3.z, f3.w));
    uint4* dst = (uint4*)(xb + i / 2);
    dst[0] = p0;
    dst[1] = p1;
    return;
  }
  if (bid >= 192) {
    // ---- W1 path: 8 e * 8 nx * 32 ks (first 1024 rows only) ----
    int b = bid - 192;
    int e = b / 256; int rr = b % 256; int nx = rr / 32, ks = rr % 32;
    w_prep_tile(W1 + (size_t)e * 1536 * 1024,
                W1p + ((size_t)(e * 8 + nx) * 32 + ks) * 4096, ks, nx, tid);
    return;
  }
  if (bid >= 64) {
    // ---- ce path ----
    int cb = bid - 64;
    int e = cb >> 4, kp = cb & 15;
    int n = tid * 4;
    const float* Wc = W1 + (size_t)e * 1536 * 1024 + (size_t)(1024 + kp * 32) * 1024 + n;
    const float* ee = emb + e * EMBD + kp * 32;
    float4 a = make_float4(0.f, 0.f, 0.f, 0.f);
#pragma unroll
    for (int kk = 0; kk < 32; ++kk) {
      float s = ee[kk];
      float4 r = *(const float4*)(Wc + (size_t)kk * 1024);
      a.x += s * r.x; a.y += s * r.y; a.z += s * r.z; a.w += s * r.w;
    }
    if (kp == 0) {
      float4 b = *(const float4*)(b1 + e * HID + n);
      a.x += b.x; a.y += b.y; a.z += b.z; a.w += b.w;
    }
    float* d = ce + e * HID + n;
    atomicAdd(d + 0, a.x); atomicAdd(d + 1, a.y);
    atomicAdd(d + 2, a.z); atomicAdd(d + 3, a.w);
    return;
  }
  // ---- bucket path (block-aggregated atomics) ----
  __shared__ int wcnt[4][NOPS];
  __shared__ int wbase[4][NOPS];
  int lane = tid & 63, w = tid >> 6;
  int t = bid * 256 + tid;
  int op = ops[t];
  unsigned long long msave = 0;
#pragma unroll
  for (int o = 0; o < NOPS; ++o) {
    unsigned long long mm = __ballot(op == o);
    if (op == o) msave = mm;
    if (lane == o) wcnt[w][o] = __popcll(mm);
  }
  __syncthreads();
  if (tid < NOPS) {
    int c0 = wcnt[0][tid], c1 = wcnt[1][tid], c2 = wcnt[2][tid], c3 = wcnt[3][tid];
    int base = atomicAdd(&cnt[tid * CNTS], c0 + c1 + c2 + c3);
    wbase[0][tid] = base;
    wbase[1][tid] = base + c0;
    wbase[2][tid] = base + c0 + c1;
    wbase[3][tid] = base + c0 + c1 + c2;
  }
  __syncthreads();
  int pre = __popcll(msave & ((1ull << lane) - 1ull));
  idx[op * BATCH + wbase[w][op] + pre] = t;
}

// ------- phase 1: GEMM1, 128x256 tiles (544 blocks) + W2 prep (2048 tail) ---
// h = relu(x_tile @ W1[e][:1024] + ce[e]); K = 1024 (32 iters).
// Round-10: each block covers an nx-PAIR -> the scattered A-gather is staged
// once per 2 output-column blocks (A tx -50%, total staging tx -25%), and the
// MFMA cluster per step doubles (32/wave ≈ 155cy cover). acc[4][8] = 128 AGPR
// -> __launch_bounds__(256,2) so the allocator doesn't spill. LDS 24KB/buf x3.
// LINE-MERGED A-gather (round-8, kept): 4 consecutive lanes fetch the 4 16B
// quarters of ONE token row's 64B ks-slice; source k-quarter XOR-swizzled by
// (row>>1)&3 so fragment ds_reads are conflict-free.
__global__ __launch_bounds__(256, 2) void gemm1_w2_k(
    const unsigned int* __restrict__ xb, const int* __restrict__ idx,
    const float* __restrict__ ce, const short* __restrict__ W1p,
    unsigned short* __restrict__ hp, const int* __restrict__ cnt,
    const float* __restrict__ W2, short* __restrict__ W2p) {
  int bid = blockIdx.x;
  int tid = threadIdx.x;
  if (bid >= 544) {
    // ---- W2 path: 8 e * 8 nx * 32 ks (tail backfill) ----
    int b = bid - 544;
    int e = b / 256; int rr = b % 256; int nx = rr / 32, ks = rr % 32;
    w_prep_tile(W2 + (size_t)e * 1024 * 1024,
                W2p + ((size_t)(e * 8 + nx) * 32 + ks) * 4096, ks, nx, tid);
    return;
  }
  int g, nx2;
  decode_bid2(bid, g, nx2);
  int rs, ce_cnt;
  int e = decode_tile(cnt, g, rs, ce_cnt);
  if (e < 0) return;

  __shared__ __align__(16) char smem[73728];   // 3 x (8KB A + 8KB B0 + 8KB B1)
  char* s0 = smem;
  char* s1 = smem + 24576;
  char* s2 = smem + 49152;

  int lane = tid & 63, w = tid >> 6;
  int wm = w >> 1, wn = w & 1;
  int fr = lane & 15, fq = lane >> 4;

  // A-gather roles: wave w stages rows w*32 .. w*32+31 (2 instrs of 16 rows).
  // lane -> (row_local = lane>>2, phys quarter = lane&3); source quarter
  // q_src = (lane&3) ^ ((lane>>3)&3)  [= phys ^ ((row>>1)&3)].
  int r0 = w * 32 + (lane >> 2);
  int r1 = r0 + 16;
  int qs = (lane & 3) ^ ((lane >> 3) & 3);
  int pp0 = rs + r0, pp1 = rs + r1;
  int t0 = (pp0 < ce_cnt) ? idx[e * BATCH + pp0] : 0;
  int t1 = (pp1 < ce_cnt) ? idx[e * BATCH + pp1] : 0;
  const char* pa0 = (const char*)xb + (size_t)t0 * 2048 + qs * 16;
  const char* pa1 = (const char*)xb + (size_t)t1 * 2048 + qs * 16;
  // two B slabs: nx = 2*nx2 and 2*nx2+1 (slabs are 262144 B apart)
  const char* pb00 = (const char*)W1p + (size_t)(e * 8 + nx2 * 2) * 32 * 8192
                     + w * 1024 + lane * 16;
  const char* pb01 = pb00 + 4096;
  const char* pb10 = pb00 + 262144;
  const char* pb11 = pb10 + 4096;

#define G1_STAGE(NB)                                                          \
  {                                                                           \
    lds_load16((NB) + w * 2048,         pa0);                                 \
    lds_load16((NB) + w * 2048 + 1024,  pa1);                                 \
    lds_load16((NB) + 8192 + w * 1024,  pb00);                                \
    lds_load16((NB) + 12288 + w * 1024, pb01);                                \
    lds_load16((NB) + 16384 + w * 1024, pb10);                                \
    lds_load16((NB) + 20480 + w * 1024, pb11);                                \
    pa0 += 64; pa1 += 64;                                                     \
    pb00 += 8192; pb01 += 8192; pb10 += 8192; pb11 += 8192;                   \
  }

#define G1_COMP(CB)                                                           \
  {                                                                           \
    const short* lA_  = (const short*)(CB);                                   \
    const short* lB0_ = (const short*)((CB) + 8192);                          \
    const short* lB1_ = (const short*)((CB) + 16384);                         \
    bf16x8 af[4], bfr[8];                                                     \
    _Pragma("unroll")                                                         \
    for (int i = 0; i < 4; ++i) af[i] = *(const bf16x8*)&lA_[fo + i * 512];   \
    _Pragma("unroll")                                                         \
    for (int j = 0; j < 4; ++j) {                                             \
      bfr[j]     = *(const bf16x8*)&lB0_[bo + j * 128];                       \
      bfr[4 + j] = *(const bf16x8*)&lB1_[bo + j * 128];                       \
    }                                                                         \
    _Pragma("unroll")                                                         \
    for (int i = 0; i < 4; ++i)                                               \
      _Pragma("unroll")                                                       \
      for (int jj = 0; jj < 8; ++jj)                                          \
        acc[i][jj] = __builtin_amdgcn_mfma_f32_16x16x32_bf16(af[i], bfr[jj],  \
                                                             acc[i][jj], 0, 0, 0); \
  }

#define G1_STEP(CB, NB)                                                       \
  {                                                                           \
    G1_STAGE(NB);                                                             \
    G1_COMP(CB);                                                              \
    VMWAIT(6);                                                                \
    BARRIER_FENCED();                                                         \
  }

  // prologue: stage ks=0 -> s0, ks=1 -> s1; wait for s0's 6 (s1's stay in flight)
  G1_STAGE(s0);
  G1_STAGE(s1);
  VMWAIT(6);
  BARRIER_FENCED();

  f32x4 acc[4][8] = {};
  // A frag: row = wm*64+i*16+fr, phys quarter = fq ^ ((fr>>1)&3)
  int fo = (wm * 64 + fr) * 32 + (fq ^ ((fr >> 1) & 3)) * 8;  // shorts, +i*512
  int bo = (fq * 128 + wn * 64 + fr) * 8;                     // B-frag base

  for (int it = 0; it < 10; ++it) {         // ks = 0..29
    G1_STEP(s0, s2);
    G1_STEP(s1, s0);
    G1_STEP(s2, s1);
  }
  // ks = 30 (s0); then drain for ks = 31 (s1)
  G1_COMP(s0);
  VMWAIT(0);
  BARRIER_FENCED();
  G1_COMP(s1);

#undef G1_STEP
#undef G1_COMP
#undef G1_STAGE

  // epilogue: +ce + relu + bf16, via LDS round-trip, looped over nx-halves.
  // hp layout (fq-major): [g][ks2(32)][kq(4)][128 r][8 k].
  float bias[2][4];
#pragma unroll
  for (int h = 0; h < 2; ++h)
#pragma unroll
    for (int j = 0; j < 4; ++j)
      bias[h][j] = ce[e * HID + (nx2 * 2 + h) * 128 + wn * 64 + j * 16 + fr];

  int lr = lane >> 2;
#pragma unroll
  for (int h = 0; h < 2; ++h) {
    int nx = nx2 * 2 + h;
#pragma unroll
    for (int i = 0; i < 4; ++i) {
      __syncthreads();
#pragma unroll
      for (int j = 0; j < 4; ++j)
#pragma unroll
        for (int rg = 0; rg < 4; ++rg) {
          float v = acc[i][h * 4 + j][rg] + bias[h][j];
          v = v > 0.f ? v : 0.f;
          int row16 = fq * 4 + rg;
          int off = w * 2048 + row16 * 128 + (j * 16 + fr) * 2;
          off ^= (row16 & 1) << 6;
          *(unsigned short*)(smem + off) = f2bf(v);
        }
      __syncthreads();
      int R = wm * 64 + i * 16 + lr;
#pragma unroll
      for (int s = 0; s < 2; ++s) {
        int ch = (lane & 3) + s * 4;
        int off = w * 2048 + lr * 128 + ch * 16;
        off ^= (lr & 1) << 6;
        uint4 val = *(const uint4*)(smem + off);
        int ks2 = nx * 4 + wn * 2 + (ch >> 2);
        int kq = ch & 3;
        *(uint4*)(hp + (((size_t)(g * 32 + ks2) * 4 + kq) * 128 + R) * 8) = val;
      }
    }
  }
}

// ---------------- phase 2: GEMM2  out[tok] = relu(h @ W2[e] + b2[e]) ---------
__global__ __launch_bounds__(256, 3) void gemm2_k(
    const unsigned short* __restrict__ hp, const float* __restrict__ b2,
    const short* __restrict__ W2p, float* __restrict__ out,
    const int* __restrict__ idx, const int* __restrict__ cnt) {
  int g, nx;
  decode_bid(blockIdx.x, g, nx);
  int rs, ce_cnt;
  int e = decode_tile(cnt, g, rs, ce_cnt);
  if (e < 0) return;

  __shared__ __align__(16) char smem[49152];   // 3 x (8KB A + 8KB B)
  __shared__ int toks[128];
  char* s0 = smem;
  char* s1 = smem + 16384;
  char* s2 = smem + 32768;

  int tid = threadIdx.x, lane = tid & 63, w = tid >> 6;
  int wm = w >> 1, wn = w & 1;
  int fr = lane & 15, fq = lane >> 4;

  if (tid < 128) {
    int p = rs + tid;
    toks[tid] = (p < ce_cnt) ? idx[e * BATCH + p] : 0;
  }

  const char* Asrc = (const char*)hp + (size_t)g * 32 * 8192;
  const char* Bsrc = (const char*)W2p + (size_t)(e * 8 + nx) * 32 * 8192;
  const char* pA0 = Asrc + w * 1024 + lane * 16;
  const char* pA1 = pA0 + 4096;
  const char* pB0 = Bsrc + w * 1024 + lane * 16;
  const char* pB1 = pB0 + 4096;

#define G2_STAGE(NB)                                                          \
  {                                                                           \
    lds_load16((NB) + w * 1024,         pA0);                                 \
    lds_load16((NB) + 4096 + w * 1024,  pA1);                                 \
    lds_load16((NB) + 8192 + w * 1024,  pB0);                                 \
    lds_load16((NB) + 12288 + w * 1024, pB1);                                 \
    pA0 += 8192; pA1 += 8192; pB0 += 8192; pB1 += 8192;                       \
  }

#define G2_COMP(CB)                                                           \
  {                                                                           \
    const short* lA_ = (const short*)(CB);                                    \
    const short* lB_ = (const short*)((CB) + 8192);                           \
    bf16x8 af[4], bfr[4];                                                     \
    _Pragma("unroll")                                                         \
    for (int i = 0; i < 4; ++i) af[i] = *(const bf16x8*)&lA_[fo + i * 128];   \
    _Pragma("unroll")                                                         \
    for (int j = 0; j < 4; ++j) bfr[j] = *(const bf16x8*)&lB_[bo + j * 128];  \
    _Pragma("unroll")                                                         \
    for (int i = 0; i < 4; ++i)                                               \
      _Pragma("unroll")                                                       \
      for (int j = 0; j < 4; ++j)                                             \
        acc[i][j] = __builtin_amdgcn_mfma_f32_16x16x32_bf16(af[i], bfr[j],    \
                                                            acc[i][j], 0, 0, 0); \
  }

#define G2_STEP(CB, NB)                                                       \
  {                                                                           \
    G2_STAGE(NB);                                                             \
    G2_COMP(CB);                                                              \
    VMWAIT(4);                                                                \
    BARRIER_FENCED();                                                         \
  }

  // prologue: stage ks=0 -> s0, ks=1 -> s1
  G2_STAGE(s0);
  G2_STAGE(s1);
  VMWAIT(4);
  BARRIER_FENCED();

  f32x4 acc[4][4] = {};
  int fo = (fq * 128 + wm * 64 + fr) * 8;
  int bo = (fq * 128 + wn * 64 + fr) * 8;

  for (int it = 0; it < 10; ++it) {         // ks = 0..29
    G2_STEP(s0, s2);
    G2_STEP(s1, s0);
    G2_STEP(s2, s1);
  }
  G2_COMP(s0);          // ks = 30
  VMWAIT(0);
  BARRIER_FENCED();
  G2_COMP(s1);          // ks = 31

#undef G2_STEP
#undef G2_COMP
#undef G2_STAGE

  // epilogue: bias + relu + scatter to out rows, coalesced via LDS round-trip.
  float bias[4];
#pragma unroll
  for (int j = 0; j < 4; ++j)
    bias[j] = b2[e * HID + nx * 128 + wn * 64 + j * 16 + fr];

  int lr = lane >> 2;
#pragma unroll
  for (int i = 0; i < 4; ++i) {
    __syncthreads();
#pragma unroll
    for (int j = 0; j < 4; ++j)
#pragma unroll
      for (int rg = 0; rg < 4; ++rg) {
        float v = acc[i][j][rg] + bias[j];
        int row16 = fq * 4 + rg;
        int off = w * 4096 + row16 * 256 + (j * 16 + fr) * 4;
        off ^= (row16 & 1) << 6;
        *(float*)(smem + off) = v > 0.f ? v : 0.f;
      }
    __syncthreads();
    int R = wm * 64 + i * 16 + lr;
    if (R < ce_cnt - rs) {
      float* orow = out + (size_t)toks[R] * HID + nx * 128 + wn * 64;
#pragma unroll
      for (int s = 0; s < 4; ++s) {
        int ch = (lane & 3) + s * 4;
        int off = w * 4096 + lr * 256 + ch * 16;
        off ^= (lr & 1) << 6;
        *(float4*)(orow + ch * 4) = *(const float4*)(smem + off);
      }
    }
  }
}

// ---------------- workspace layout (bytes) ----------------
// cnt     @ 0          (512)          — zeroed (with ce) by one memset
// ce      @ 512        (32768)        -> 33280
// idx     @ 36864      (524288)       -> 561152
// W1p     @ 561152     (16777216)     -> 17338368
// W2p     @ 17338368   (16777216)     -> 34115584
// hp      @ 34115584   (35651584)     -> 69767168
// xb      @ 69767168   (33554432)     -> 103321600 (~103.3 MB)

extern "C" void kernel_launch(void* const* d_in, const int* in_sizes, int n_in,
                              void* d_out, int out_size, void* d_ws, size_t ws_size,
                              hipStream_t stream) {
  const float* x   = (const float*)d_in[0];
  const int*   ops = (const int*)d_in[1];
  const float* emb = (const float*)d_in[2];
  const float* W1  = (const float*)d_in[3];
  const float* b1  = (const float*)d_in[4];
  const float* W2  = (const float*)d_in[5];
  const float* b2  = (const float*)d_in[6];
  float* out = (float*)d_out;

  char* ws = (char*)d_ws;
  int* cnt  = (int*)(ws + 0);
  float* ce = (float*)(ws + 512);
  int* idx  = (int*)(ws + 36864);
  short* W1p = (short*)(ws + 561152);
  short* W2p = (short*)(ws + 17338368);
  unsigned short* hp = (unsigned short*)(ws + 34115584);
  unsigned int* xb = (unsigned int*)(ws + 69767168);

  hipMemsetAsync(ws, 0, 33280, stream);   // cnt + ce
  bucket_ce_k<<<2240 + 4096, 256, 0, stream>>>(ops, cnt, idx, W1, emb, b1, ce, W1p, x, xb);
  gemm1_w2_k<<<544 + 2048, 256, 0, stream>>>(xb, idx, ce, W1p, hp, cnt, W2, W2p);
  gemm2_k<<<8 * MAXT, 256, 0, stream>>>(hp, b2, W2p, out, idx, cnt);
}